// Round 1
// 472.437 us; speedup vs baseline: 1.0806x; 1.0806x over previous
//
#include <hip/hip_runtime.h>

#define CURV 2.3026f
#define EPSF 1e-15f

typedef __attribute__((ext_vector_type(8))) short bfrag8;
typedef __attribute__((ext_vector_type(4))) float ffrag4;

static __device__ __forceinline__ unsigned short f2bf(float f) {
  unsigned u = __builtin_bit_cast(unsigned, f);
  u += 0x7fffu + ((u >> 16) & 1u);
  return (unsigned short)(u >> 16);
}

// async global->LDS, 16B per lane; LDS dest = wave-uniform base + lane*16 (global side is per-lane)
static __device__ __forceinline__ void gld16(const void* g, void* l) {
  unsigned lo = (unsigned)(unsigned long long)l;
  __builtin_amdgcn_global_load_lds(
      (const __attribute__((address_space(1))) unsigned int*)g,
      (__attribute__((address_space(3))) unsigned int*)lo, 16, 0, 0);
}

// ---- weight prep: bf16 transpose + per-column stats {2(zn-1), cosh(tcr)/zn, sinh(tcr), 0} ----
__global__ void prep_weights(const float* __restrict__ z, const float* __restrict__ r,
                             unsigned short* __restrict__ zT, float* __restrict__ stats,
                             int K, int N) {
  int n = blockIdx.x, t = threadIdx.x;  // 128 threads
  float ss = 0.f;
  for (int k = t; k < K; k += 128) {
    float v = z[(size_t)k * N + n];
    ss += v * v;
    zT[(size_t)n * K + k] = f2bf(v);
  }
  __shared__ float red[128];
  red[t] = ss; __syncthreads();
  for (int s = 64; s > 0; s >>= 1) { if (t < s) red[t] += red[t + s]; __syncthreads(); }
  if (t == 0) {
    float zn = fmaxf(sqrtf(red[0]), EPSF);
    float cs = sqrtf(CURV);
    float tc = 2.f * cs * r[n];
    stats[4*n+0] = 2.f * (zn - 1.f);
    stats[4*n+1] = coshf(tc) / zn;
    stats[4*n+2] = sinhf(tc);
    stats[4*n+3] = 0.f;
  }
}

// s -> w via polynomial sinh(2*zn*asinh(g)) expansion (|g|<~0.35, |delta|<~0.16); in place on acc
template<int NT>
static __device__ __forceinline__ void poly_w(ffrag4 (&acc)[2][NT], const float* __restrict__ stats,
                                              int wn, int lm, int wm, int quad,
                                              const float* lamP, float cs, float inv_cs) {
#pragma unroll
  for (int tn = 0; tn < NT; tn++) {
    float4 st = *(const float4*)(stats + 4 * (wn * (16 * NT) + 16 * tn + lm));
    float dl = st.x, chozn = st.y, sh = st.z;
#pragma unroll
    for (int tm = 0; tm < 2; tm++) {
#pragma unroll
      for (int rg = 0; rg < 4; rg++) {
        float lam = lamP[32 * wm + 16 * tm + 4 * quad + rg];
        float g = cs * lam * acc[tm][tn][rg] * chozn - (lam - 1.f) * sh;
        float q = g * g;
        float u = g * (1.f - q * (1.f / 6.f) + q * q * 0.075f - q * q * q * 0.044642857f);
        float d1 = dl * u;
        float S = 2.f * g * sqrtf(1.f + q);
        float Ch = 1.f + 2.f * q;
        acc[tm][tn][rg] = (S * (1.f + 0.5f * d1 * d1) + Ch * d1) * inv_cs;
      }
    }
  }
}

// row reductions: sum w^2, sum relu(w)^2, (L4) sum relu(w)*z4
template<int NT, bool L4>
static __device__ __forceinline__ void reduce_rows(ffrag4 (&acc)[2][NT], const float* z4v,
                                                   int lm, int wm, int quad, float (*sums_)[64]) {
#pragma unroll
  for (int tm = 0; tm < 2; tm++) {
#pragma unroll
    for (int rg = 0; rg < 4; rg++) {
      float s2 = 0.f, sp2 = 0.f, s4 = 0.f;
#pragma unroll
      for (int tn = 0; tn < NT; tn++) {
        float w = acc[tm][tn][rg];
        s2 += w * w;
        float wp = fmaxf(w, 0.f);
        sp2 += wp * wp;
        if (L4) s4 += wp * z4v[tn];
      }
#pragma unroll
      for (int m = 1; m <= 8; m <<= 1) {
        s2 += __shfl_xor(s2, m, 16);
        sp2 += __shfl_xor(sp2, m, 16);
        if (L4) s4 += __shfl_xor(s4, m, 16);
      }
      if (lm == 0) {
        int row = 32 * wm + 16 * tm + 4 * quad + rg;
        atomicAdd(&sums_[0][row], s2);
        atomicAdd(&sums_[1][row], sp2);
        if (L4) atomicAdd(&sums_[2][row], s4);
      }
    }
  }
}

// write h = gam*relu(w) as bf16 into a panel of 4KB k-tiles, each in the paired-row
// swizzled A-staging layout: data (row r, 16B-chunk c in [0,8)) of k-tile kt lives at
// kt*4096 + (r>>1)*128 + ((4*(r&1)+c) ^ ((r>>1)&7))*16.  Matches the afoff frag reads.
template<int NT>
static __device__ __forceinline__ void panel_write(ffrag4 (&acc)[2][NT], char* panel,
                                                   int lm, int wm, int wn, int quad,
                                                   const float* gamP) {
#pragma unroll
  for (int tm = 0; tm < 2; tm++)
#pragma unroll
    for (int rg = 0; rg < 4; rg++) {
      const int r = 32 * wm + 16 * tm + 4 * quad + rg;
      const float gam = gamP[r];
      const unsigned rb = (unsigned)((r >> 1) * 128);
      const unsigned rx = (unsigned)((r >> 1) & 7);
      const unsigned c0 = (unsigned)((r & 1) * 4);
#pragma unroll
      for (int tn = 0; tn < NT; tn++) {
        const int col = wn * (16 * NT) + 16 * tn + lm;
        const unsigned ad = (unsigned)((col >> 5) * 4096) + rb +
                            (((c0 + (unsigned)((col >> 3) & 3)) ^ rx) << 4) +
                            (unsigned)((col & 7) * 2);
        *(unsigned short*)(panel + ad) = f2bf(gam * fmaxf(acc[tm][tn][rg], 0.f));
      }
    }
}

// ---- fully fused 4-layer Poincare MLP: 64 rows/block, 16 waves (2M x 8N), 1024 blocks.
// Phase 1: x fp32 staged via gld16 (dbuf) + converted in-flight (ss for lambda0 on the fly),
//          B1 staged dbuf. Phase 2/3: A-frags read from persistent LDS h-panels (no A staging),
//          only B staged; B prologues issued during the preceding epilogue to hide latency.
// LDS overlay (96KB + 1.3KB extras -> 1 block/CU, 16 waves resident):
//   [0,16K) A1 dbuf -> later B3 dbuf;  [16K,80K) B1 dbuf;  [0,64K) h1 panel (after ph1);
//   [64K,96K) B2 dbuf -> later h2 panel. All overlays are barrier-separated.
__launch_bounds__(1024, 4)
__global__ void fused_mlp(const float* __restrict__ x,
                          const unsigned short* __restrict__ zt1, const float* __restrict__ st1,
                          const unsigned short* __restrict__ zt2, const float* __restrict__ st2,
                          const unsigned short* __restrict__ zt3, const float* __restrict__ st3,
                          const float* __restrict__ z4, const float* __restrict__ st4,
                          float* __restrict__ outF) {
  __shared__ __align__(16) char smem[98304];
  __shared__ float lamS[64];
  __shared__ float gamS[64];
  __shared__ float sums[3][64];

  const int t = threadIdx.x;
  const int wid = t >> 6, lane = t & 63;
  const int wm = wid >> 3, wn = wid & 7;
  const int lm = lane & 15, quad = lane >> 4;
  const int l7 = lane & 7, rl8 = lane >> 3;
  const unsigned rowg0 = blockIdx.x * 64u;

  char* const A1 = smem;           // 2 x 8KB fp32 x tiles
  char* const B1 = smem + 16384;   // 2 x 32KB
  char* const H1 = smem;           // 64KB panel (16 k-tiles)
  char* const B2 = smem + 65536;   // 2 x 16KB
  char* const H2 = smem + 65536;   // 32KB panel (8 k-tiles)
  char* const B3 = smem;           // 2 x 8KB

  const unsigned cA = (unsigned)(l7 ^ rl8);        // stored-chunk index for staging lanes
  const unsigned ldst = (unsigned)(lane * 16);

  // frag-read offsets. bf16 paired-row k-tile: slot = (((lm&1)<<2)+quad) ^ (lm>>1)
  const unsigned sl16 = (unsigned)(((((lm & 1) << 2) + quad) ^ (lm >> 1)) << 4);
  unsigned afoff[2];
#pragma unroll
  for (int tm = 0; tm < 2; tm++) afoff[tm] = (unsigned)((16 * wm + 8 * tm + (lm >> 1)) * 128) + sl16;
  // fp32 x tile: row-major 64 rows x 128B, chunk c at slot c^(r&7); lane reads chunks 2q,2q+1
  unsigned a32off[2][2];
#pragma unroll
  for (int tm = 0; tm < 2; tm++) {
    int r = 32 * wm + 16 * tm + lm;
#pragma unroll
    for (int j = 0; j < 2; j++)
      a32off[tm][j] = (unsigned)(r * 128 + (((2 * quad + j) ^ (r & 7)) * 16));
  }
  unsigned bf1off[4];
#pragma unroll
  for (int tn = 0; tn < 4; tn++) bf1off[tn] = (unsigned)((wn * 32 + 8 * tn + (lm >> 1)) * 128) + sl16;
  unsigned bf2off[2];
#pragma unroll
  for (int tn = 0; tn < 2; tn++) bf2off[tn] = (unsigned)((wn * 16 + 8 * tn + (lm >> 1)) * 128) + sl16;
  const unsigned bf3off = (unsigned)((wn * 8 + (lm >> 1)) * 128) + sl16;

  // staging addresses
  unsigned a1src = 0;
  if (wid < 8) a1src = (rowg0 + 8u * (unsigned)wid + (unsigned)rl8) * 3072u + cA * 16u;
  const unsigned a1dst = (unsigned)(wid * 1024) + ldst;   // used only when wid<8
  unsigned b1src[2], b1dst[2];
#pragma unroll
  for (int j = 0; j < 2; j++) {
    unsigned R = (unsigned)(8 * (wid + 16 * j) + rl8);
    unsigned n = 2u * R + (cA >> 2);
    b1src[j] = n * 1536u + (cA & 3u) * 16u;
    b1dst[j] = (unsigned)((wid + 16 * j) * 1024) + ldst;
  }
  const unsigned R2 = (unsigned)(8 * wid + rl8);
  const unsigned b2src = (2u * R2 + (cA >> 2)) * 1024u + (cA & 3u) * 16u;
  const unsigned b2dst = (unsigned)(wid * 1024) + ldst;
  const unsigned b3src = (2u * R2 + (cA >> 2)) * 512u + (cA & 3u) * 16u;  // wid<8 only

  // ================= phase 1: (64x768 fp32 -> bf16) @ zT1 -> 64x512 =================
  if (wid < 8) gld16((const char*)x + a1src, A1 + a1dst);
  gld16((const char*)zt1 + b1src[0], B1 + b1dst[0]);
  gld16((const char*)zt1 + b1src[1], B1 + b1dst[1]);

  ffrag4 acc1[2][4];
#pragma unroll
  for (int a = 0; a < 2; a++)
#pragma unroll
    for (int b = 0; b < 4; b++) acc1[a][b] = (ffrag4){0.f, 0.f, 0.f, 0.f};
  float ss0 = 0.f, ss1 = 0.f;

  for (int k = 0; k < 24; k++) {
    __syncthreads();
    char* curA = A1 + (k & 1) * 8192;
    char* curB = B1 + (k & 1) * 32768;
    if (k + 1 < 24) {
      char* nA = A1 + ((k + 1) & 1) * 8192;
      char* nB = B1 + ((k + 1) & 1) * 32768;
      unsigned advA = (unsigned)(k + 1) * 128u;
      unsigned advB = (unsigned)(k + 1) * 64u;
      if (wid < 8) gld16((const char*)x + a1src + advA, nA + a1dst);
      gld16((const char*)zt1 + b1src[0] + advB, nB + b1dst[0]);
      gld16((const char*)zt1 + b1src[1] + advB, nB + b1dst[1]);
    }
    bfrag8 af[2];
#pragma unroll
    for (int tm = 0; tm < 2; tm++) {
      float4 fa = *(const float4*)(curA + a32off[tm][0]);
      float4 fb = *(const float4*)(curA + a32off[tm][1]);
      if (wn == 0) {  // wave-uniform: only wid 0 and 8 accumulate ||x||^2
        float s = fa.x * fa.x + fa.y * fa.y + fa.z * fa.z + fa.w * fa.w
                + fb.x * fb.x + fb.y * fb.y + fb.z * fb.z + fb.w * fb.w;
        if (tm == 0) ss0 += s; else ss1 += s;
      }
      bfrag8 v;
      v[0] = (short)f2bf(fa.x); v[1] = (short)f2bf(fa.y);
      v[2] = (short)f2bf(fa.z); v[3] = (short)f2bf(fa.w);
      v[4] = (short)f2bf(fb.x); v[5] = (short)f2bf(fb.y);
      v[6] = (short)f2bf(fb.z); v[7] = (short)f2bf(fb.w);
      af[tm] = v;
    }
#pragma unroll
    for (int tn = 0; tn < 4; tn++) {
      bfrag8 bf = *(const bfrag8*)(curB + bf1off[tn]);
      acc1[0][tn] = __builtin_amdgcn_mfma_f32_16x16x32_bf16(af[0], bf, acc1[0][tn], 0, 0, 0);
      acc1[1][tn] = __builtin_amdgcn_mfma_f32_16x16x32_bf16(af[1], bf, acc1[1][tn], 0, 0, 0);
    }
  }

  // lambda0 from fp32 ss (frag lane holds row 32*wm+16*tm+lm, octet=quad; reduce over quads)
  if (wn == 0) {
    ss0 += __shfl_xor(ss0, 16); ss0 += __shfl_xor(ss0, 32);
    ss1 += __shfl_xor(ss1, 16); ss1 += __shfl_xor(ss1, 32);
    if (quad == 0) {
      lamS[32 * wm + lm]      = 2.f / (1.f - CURV * ss0);
      lamS[32 * wm + 16 + lm] = 2.f / (1.f - CURV * ss1);
    }
  }
  if (t < 64) { sums[0][t] = 0.f; sums[1][t] = 0.f; }
  __syncthreads();  // phase-1 LDS reads done; lamS/sums visible

  // B2 prologue (steps 0,1) hidden under epilogue-1; overlays dead B1 tail
  gld16((const char*)zt2 + b2src, B2 + b2dst);
  gld16((const char*)zt2 + b2src + 64u, B2 + 16384 + b2dst);

  const float cs = sqrtf(CURV), inv_cs = 1.f / cs;
  poly_w<4>(acc1, st1, wn, lm, wm, quad, lamS, cs, inv_cs);
  reduce_rows<4, false>(acc1, nullptr, lm, wm, quad, sums);
  __syncthreads();
  if (t < 64) {
    float sw2 = sums[0][t], swp2 = sums[1][t];
    float den = 1.f + sqrtf(1.f + CURV * sw2);
    float nn = fmaxf(sqrtf(sw2) / den, EPSF);
    float al = atanhf(fminf(cs * nn, 1.f - 1e-7f)) / (cs * nn);
    float vn = fmaxf(al * sqrtf(swp2) / den, EPSF);
    float be = tanhf(cs * vn) / (cs * vn);
    float gam = al * be / den;
    gamS[t] = gam;
    lamS[t] = 2.f / (1.f - CURV * gam * gam * swp2);
  }
  __syncthreads();
  panel_write<4>(acc1, H1, lm, wm, wn, quad, gamS);  // h1 panel overlays dead A1/B1

  // ================= phase 2: h1(64x512) @ zT2 -> 64x256 =================
  ffrag4 acc2[2][2];
#pragma unroll
  for (int a = 0; a < 2; a++)
#pragma unroll
    for (int b = 0; b < 2; b++) acc2[a][b] = (ffrag4){0.f, 0.f, 0.f, 0.f};
  if (t < 64) { sums[0][t] = 0.f; sums[1][t] = 0.f; }

  for (int k = 0; k < 16; k++) {
    __syncthreads();  // k=0: drains B2 prologue + makes h1 panel visible
    char* curB = B2 + (k & 1) * 16384;
    if (k > 0 && k + 1 < 16)
      gld16((const char*)zt2 + b2src + (unsigned)(k + 1) * 64u,
            B2 + ((k + 1) & 1) * 16384 + b2dst);
    bfrag8 a0 = *(const bfrag8*)(H1 + k * 4096 + afoff[0]);
    bfrag8 a1 = *(const bfrag8*)(H1 + k * 4096 + afoff[1]);
#pragma unroll
    for (int tn = 0; tn < 2; tn++) {
      bfrag8 bf = *(const bfrag8*)(curB + bf2off[tn]);
      acc2[0][tn] = __builtin_amdgcn_mfma_f32_16x16x32_bf16(a0, bf, acc2[0][tn], 0, 0, 0);
      acc2[1][tn] = __builtin_amdgcn_mfma_f32_16x16x32_bf16(a1, bf, acc2[1][tn], 0, 0, 0);
    }
  }
  __syncthreads();  // phase-2 reads of H1/B2 done

  // B3 prologue hidden under epilogue-2; overlays dead h1 k-tiles 0-3
  if (wid < 8) {
    gld16((const char*)zt3 + b3src, B3 + b2dst);
    gld16((const char*)zt3 + b3src + 64u, B3 + 8192 + b2dst);
  }
  poly_w<2>(acc2, st2, wn, lm, wm, quad, lamS, cs, inv_cs);
  reduce_rows<2, false>(acc2, nullptr, lm, wm, quad, sums);
  __syncthreads();
  if (t < 64) {
    float sw2 = sums[0][t], swp2 = sums[1][t];
    float den = 1.f + sqrtf(1.f + CURV * sw2);
    float nn = fmaxf(sqrtf(sw2) / den, EPSF);
    float al = atanhf(fminf(cs * nn, 1.f - 1e-7f)) / (cs * nn);
    float vn = fmaxf(al * sqrtf(swp2) / den, EPSF);
    float be = tanhf(cs * vn) / (cs * vn);
    float gam = al * be / den;
    gamS[t] = gam;
    lamS[t] = 2.f / (1.f - CURV * gam * gam * swp2);
  }
  __syncthreads();
  panel_write<2>(acc2, H2, lm, wm, wn, quad, gamS);  // h2 panel overlays dead B2

  // ================= phase 3: h2(64x256) @ zT3 -> 64x128, + layer 4 dot =================
  ffrag4 acc3[2][1];
  acc3[0][0] = (ffrag4){0.f, 0.f, 0.f, 0.f};
  acc3[1][0] = (ffrag4){0.f, 0.f, 0.f, 0.f};
  if (t < 64) { sums[0][t] = 0.f; sums[1][t] = 0.f; sums[2][t] = 0.f; }
  float z4v[1] = { z4[wn * 16 + lm] };

  for (int k = 0; k < 8; k++) {
    __syncthreads();  // k=0: drains B3 prologue + makes h2 panel visible
    char* curB = B3 + (k & 1) * 8192;
    if (k > 0 && k + 1 < 8 && wid < 8)
      gld16((const char*)zt3 + b3src + (unsigned)(k + 1) * 64u,
            B3 + ((k + 1) & 1) * 8192 + b2dst);
    bfrag8 a0 = *(const bfrag8*)(H2 + k * 4096 + afoff[0]);
    bfrag8 a1 = *(const bfrag8*)(H2 + k * 4096 + afoff[1]);
    bfrag8 bf = *(const bfrag8*)(curB + bf3off);
    acc3[0][0] = __builtin_amdgcn_mfma_f32_16x16x32_bf16(a0, bf, acc3[0][0], 0, 0, 0);
    acc3[1][0] = __builtin_amdgcn_mfma_f32_16x16x32_bf16(a1, bf, acc3[1][0], 0, 0, 0);
  }
  __syncthreads();

  poly_w<1>(acc3, st3, wn, lm, wm, quad, lamS, cs, inv_cs);
  reduce_rows<1, true>(acc3, z4v, lm, wm, quad, sums);
  __syncthreads();
  if (t < 64) {
    float sw2 = sums[0][t], swp2 = sums[1][t];
    float den = 1.f + sqrtf(1.f + CURV * sw2);
    float nn = fmaxf(sqrtf(sw2) / den, EPSF);
    float al = atanhf(fminf(cs * nn, 1.f - 1e-7f)) / (cs * nn);
    float vn = fmaxf(al * sqrtf(swp2) / den, EPSF);
    float be = tanhf(cs * vn) / (cs * vn);
    float gam = al * be / den;
    float s = gam * sums[2][t];
    float lamh = 2.f / (1.f - CURV * gam * gam * swp2);
    float g = cs * lamh * s * st4[1] - (lamh - 1.f) * st4[2];
    float q = g * g;
    float u = g * (1.f - q * (1.f / 6.f) + q * q * 0.075f - q * q * q * 0.044642857f);
    float d1 = st4[0] * u;
    float S = 2.f * g * sqrtf(1.f + q);
    float Ch = 1.f + 2.f * q;
    float w = (S * (1.f + 0.5f * d1 * d1) + Ch * d1) * inv_cs;
    outF[rowg0 + t] = w / (1.f + sqrtf(1.f + CURV * w * w));
  }
}

extern "C" void kernel_launch(void* const* d_in, const int* in_sizes, int n_in,
                              void* d_out, int out_size, void* d_ws, size_t ws_size,
                              hipStream_t stream) {
  const float* x  = (const float*)d_in[0];
  const float* z1 = (const float*)d_in[1];
  const float* b1 = (const float*)d_in[2];
  const float* z2 = (const float*)d_in[3];
  const float* b2 = (const float*)d_in[4];
  const float* z3 = (const float*)d_in[5];
  const float* b3 = (const float*)d_in[6];
  const float* z4 = (const float*)d_in[7];
  const float* b4 = (const float*)d_in[8];

  char* ws = (char*)d_ws; size_t off = 0;
  auto carve = [&](size_t b) { char* p = ws + off; off += (b + 255) & ~(size_t)255; return p; };
  unsigned short* zT1 = (unsigned short*)carve(512 * 768 * 2);
  unsigned short* zT2 = (unsigned short*)carve(256 * 512 * 2);
  unsigned short* zT3 = (unsigned short*)carve(128 * 256 * 2);
  unsigned short* zT4 = (unsigned short*)carve(128 * 2);
  float* st1 = (float*)carve(512 * 4 * 4);
  float* st2 = (float*)carve(256 * 4 * 4);
  float* st3 = (float*)carve(128 * 4 * 4);
  float* st4 = (float*)carve(4 * 4);

  prep_weights<<<512, 128, 0, stream>>>(z1, b1, zT1, st1, 768, 512);
  prep_weights<<<256, 128, 0, stream>>>(z2, b2, zT2, st2, 512, 256);
  prep_weights<<<128, 128, 0, stream>>>(z3, b3, zT3, st3, 256, 128);
  prep_weights<<<1,   128, 0, stream>>>(z4, b4, zT4, st4, 128, 1);

  fused_mlp<<<1024, 1024, 0, stream>>>(x, zT1, st1, zT2, st2, zT3, st3, z4, st4, (float*)d_out);
}

// Round 2
// 450.946 us; speedup vs baseline: 1.1321x; 1.0477x over previous
//
#include <hip/hip_runtime.h>

#define CURV 2.3026f
#define EPSF 1e-15f

typedef __attribute__((ext_vector_type(8))) short bfrag8;
typedef __attribute__((ext_vector_type(4))) float ffrag4;

static __device__ __forceinline__ unsigned short f2bf(float f) {
  unsigned u = __builtin_bit_cast(unsigned, f);
  u += 0x7fffu + ((u >> 16) & 1u);
  return (unsigned short)(u >> 16);
}

// async global->LDS, 16B per lane; LDS dest = wave-uniform base + lane*16 (global side is per-lane)
static __device__ __forceinline__ void gld16(const void* g, void* l) {
  unsigned lo = (unsigned)(unsigned long long)l;
  __builtin_amdgcn_global_load_lds(
      (const __attribute__((address_space(1))) unsigned int*)g,
      (__attribute__((address_space(3))) unsigned int*)lo, 16, 0, 0);
}

// ---- fused weight prep (all 4 layers in one launch): bf16 transpose + per-col stats ----
__global__ void prep_all(const float* __restrict__ z1, const float* __restrict__ r1,
                         const float* __restrict__ z2, const float* __restrict__ r2,
                         const float* __restrict__ z3, const float* __restrict__ r3,
                         const float* __restrict__ z4, const float* __restrict__ r4,
                         unsigned short* __restrict__ zT1, float* __restrict__ st1,
                         unsigned short* __restrict__ zT2, float* __restrict__ st2,
                         unsigned short* __restrict__ zT3, float* __restrict__ st3,
                         unsigned short* __restrict__ zT4, float* __restrict__ st4) {
  int b = blockIdx.x, t = threadIdx.x;  // 128 threads
  const float *z, *r; unsigned short* zT; float* st; int K, N, n;
  if (b < 512)      { z = z1; r = r1; zT = zT1; st = st1; K = 768; N = 512; n = b; }
  else if (b < 768) { z = z2; r = r2; zT = zT2; st = st2; K = 512; N = 256; n = b - 512; }
  else if (b < 896) { z = z3; r = r3; zT = zT3; st = st3; K = 256; N = 128; n = b - 768; }
  else              { z = z4; r = r4; zT = zT4; st = st4; K = 128; N = 1;   n = 0; }
  float ss = 0.f;
  for (int k = t; k < K; k += 128) {
    float v = z[(size_t)k * N + n];
    ss += v * v;
    zT[(size_t)n * K + k] = f2bf(v);
  }
  __shared__ float red[128];
  red[t] = ss; __syncthreads();
  for (int s = 64; s > 0; s >>= 1) { if (t < s) red[t] += red[t + s]; __syncthreads(); }
  if (t == 0) {
    float zn = fmaxf(sqrtf(red[0]), EPSF);
    float cs = sqrtf(CURV);
    float tc = 2.f * cs * r[n];
    st[4*n+0] = 2.f * (zn - 1.f);
    st[4*n+1] = coshf(tc) / zn;
    st[4*n+2] = sinhf(tc);
    st[4*n+3] = 0.f;
  }
}

// s -> w via polynomial sinh(2*zn*asinh(g)) expansion (|g|<~0.35, |delta|<~0.16); in place on acc
template<int NT>
static __device__ __forceinline__ void poly_w(ffrag4 (&acc)[2][NT], const float* __restrict__ stats,
                                              int wn, int lm, int wm, int quad,
                                              const float* lamP, float cs, float inv_cs) {
#pragma unroll
  for (int tn = 0; tn < NT; tn++) {
    float4 st = *(const float4*)(stats + 4 * (wn * (16 * NT) + 16 * tn + lm));
    float dl = st.x, chozn = st.y, sh = st.z;
#pragma unroll
    for (int tm = 0; tm < 2; tm++) {
#pragma unroll
      for (int rg = 0; rg < 4; rg++) {
        float lam = lamP[32 * wm + 16 * tm + 4 * quad + rg];
        float g = cs * lam * acc[tm][tn][rg] * chozn - (lam - 1.f) * sh;
        float q = g * g;
        float u = g * (1.f - q * (1.f / 6.f) + q * q * 0.075f - q * q * q * 0.044642857f);
        float d1 = dl * u;
        float S = 2.f * g * sqrtf(1.f + q);
        float Ch = 1.f + 2.f * q;
        acc[tm][tn][rg] = (S * (1.f + 0.5f * d1 * d1) + Ch * d1) * inv_cs;
      }
    }
  }
}

// row reductions: sum w^2, sum relu(w)^2, (L4) sum relu(w)*z4
template<int NT, bool L4>
static __device__ __forceinline__ void reduce_rows(ffrag4 (&acc)[2][NT], const float* z4v,
                                                   int lm, int wm, int quad, float (*sums_)[64]) {
#pragma unroll
  for (int tm = 0; tm < 2; tm++) {
#pragma unroll
    for (int rg = 0; rg < 4; rg++) {
      float s2 = 0.f, sp2 = 0.f, s4 = 0.f;
#pragma unroll
      for (int tn = 0; tn < NT; tn++) {
        float w = acc[tm][tn][rg];
        s2 += w * w;
        float wp = fmaxf(w, 0.f);
        sp2 += wp * wp;
        if (L4) s4 += wp * z4v[tn];
      }
#pragma unroll
      for (int m = 1; m <= 8; m <<= 1) {
        s2 += __shfl_xor(s2, m, 16);
        sp2 += __shfl_xor(sp2, m, 16);
        if (L4) s4 += __shfl_xor(s4, m, 16);
      }
      if (lm == 0) {
        int row = 32 * wm + 16 * tm + 4 * quad + rg;
        atomicAdd(&sums_[0][row], s2);
        atomicAdd(&sums_[1][row], sp2);
        if (L4) atomicAdd(&sums_[2][row], s4);
      }
    }
  }
}

// write h = gam*relu(w) as bf16 into a panel of 4KB k-tiles in the paired-row swizzled layout:
// data (row r, 16B-chunk c' in [0,4)) of k-tile kt at kt*4096 + (r>>1)*128 + ((4*(r&1)+c')^((r>>1)&7))*16
template<int NT>
static __device__ __forceinline__ void panel_write(ffrag4 (&acc)[2][NT], char* panel,
                                                   int lm, int wm, int wn, int quad,
                                                   const float* gamP) {
#pragma unroll
  for (int tm = 0; tm < 2; tm++)
#pragma unroll
    for (int rg = 0; rg < 4; rg++) {
      const int r = 32 * wm + 16 * tm + 4 * quad + rg;
      const float gam = gamP[r];
      const unsigned rb = (unsigned)((r >> 1) * 128);
      const unsigned rx = (unsigned)((r >> 1) & 7);
      const unsigned c0 = (unsigned)((r & 1) * 4);
#pragma unroll
      for (int tn = 0; tn < NT; tn++) {
        const int col = wn * (16 * NT) + 16 * tn + lm;
        const unsigned ad = (unsigned)((col >> 5) * 4096) + rb +
                            (((c0 + (unsigned)((col >> 3) & 3)) ^ rx) << 4) +
                            (unsigned)((col & 7) * 2);
        *(unsigned short*)(panel + ad) = f2bf(gam * fmaxf(acc[tm][tn][rg], 0.f));
      }
    }
}

// convert 4 fp32 -> 4 bf16, ds_write_b64 into paired-row layout; returns sum of squares
static __device__ __forceinline__ float stage_a4(float4 f, char* p) {
  ushort4 h; h.x = f2bf(f.x); h.y = f2bf(f.y); h.z = f2bf(f.z); h.w = f2bf(f.w);
  *(ushort4*)p = h;
  return f.x * f.x + f.y * f.y + f.z * f.z + f.w * f.w;
}

// ---- fully fused 4-layer Poincare MLP: 64 rows/block, 16 waves (2M x 8N), BK=64.
// Phase 1: A reg-staged (fp32->bf16 converted ONCE, ds_write_b64, ss accumulated in-flight),
//          B1 via gld16; dbuf; 12 steps. Phases 2/3: A from persistent LDS h-panels, B via
//          gld16 dbuf; 8/4 steps. B prologues issued inside the preceding epilogue.
// LDS overlay (145.3KB -> 1 block/CU, 16 waves):
//   ph1: A1 dbuf [0,16K) + B1 dbuf [16K,144K)
//   ph2: H1 [0,64K) + B2 dbuf [64K,128K)
//   ph3: H2 [0,32K) + B3 dbuf [32K,64K)     (all overlays barrier-separated)
__launch_bounds__(1024, 4)
__global__ void fused_mlp(const float* __restrict__ x,
                          const unsigned short* __restrict__ zt1, const float* __restrict__ st1,
                          const unsigned short* __restrict__ zt2, const float* __restrict__ st2,
                          const unsigned short* __restrict__ zt3, const float* __restrict__ st3,
                          const float* __restrict__ z4, const float* __restrict__ st4,
                          float* __restrict__ outF) {
  __shared__ __align__(16) char smem[147456];
  __shared__ float lamS[64];
  __shared__ float gamS[64];
  __shared__ float sums[3][64];

  const int t = threadIdx.x;
  const int wid = t >> 6, lane = t & 63;
  const int wm = wid >> 3, wn = wid & 7;
  const int lm = lane & 15, quad = lane >> 4;
  const int l7 = lane & 7, rl8 = lane >> 3;
  const unsigned rowg0 = blockIdx.x * 64u;

  char* const A1 = smem;           // 2 x 8KB bf16 x-tiles (64 rows x 64 k)
  char* const B1 = smem + 16384;   // 2 x 64KB
  char* const H1 = smem;           // 64KB panel (16 k-tiles)
  char* const B2 = smem + 65536;   // 2 x 32KB
  char* const H2 = smem;           // 32KB panel (8 k-tiles)
  char* const B3 = smem + 32768;   // 2 x 16KB

  const unsigned cB = (unsigned)(l7 ^ rl8);   // stored-chunk index for B staging lanes
  const unsigned ldst = (unsigned)(lane * 16);

  // frag-read offsets (paired-row bf16 k-tiles; slot = (((lm&1)<<2)+quad) ^ (lm>>1))
  const unsigned sl16 = (unsigned)(((((lm & 1) << 2) + quad) ^ (lm >> 1)) << 4);
  unsigned afoff[2];
#pragma unroll
  for (int tm = 0; tm < 2; tm++) afoff[tm] = (unsigned)((16 * wm + 8 * tm + (lm >> 1)) * 128) + sl16;
  unsigned bf1off[4];
#pragma unroll
  for (int tn = 0; tn < 4; tn++) bf1off[tn] = (unsigned)((wn * 32 + 8 * tn + (lm >> 1)) * 128) + sl16;
  unsigned bf2off[2];
#pragma unroll
  for (int tn = 0; tn < 2; tn++) bf2off[tn] = (unsigned)((wn * 16 + 8 * tn + (lm >> 1)) * 128) + sl16;
  const unsigned bf3off = (unsigned)((wn * 8 + (lm >> 1)) * 128) + sl16;

  // ---- A staging (phase 1): wave w owns rows 4w..4w+3; lane covers 4 fp32 at k=4*(lane&15)
  const int mrow = 4 * wid + (lane >> 4);
  const unsigned kloc = 4u * (unsigned)(lane & 15);          // fp32 element offset in 64-k tile
  const char* a1g = (const char*)x + (size_t)(rowg0 + (unsigned)mrow) * 3072 + kloc * 4u;
  const unsigned kk = kloc & 31u;
  const unsigned a1d = (kloc >> 5) * 4096u + (unsigned)(mrow >> 1) * 128u +
                       ((((unsigned)(mrow & 1) * 4u + (kk >> 3)) ^ ((unsigned)(mrow >> 1) & 7u)) << 4) +
                       ((kk >> 2) & 1u) * 8u;

  // ---- B staging addresses (paired-row subtiles; linear LDS dst, swizzled global src)
  unsigned b1s[4], b1d[4];
#pragma unroll
  for (int j = 0; j < 4; j++) {
    unsigned rr = (unsigned)(wid + 16 * j);                 // 0..63
    unsigned R = 8u * (rr & 31u) + (unsigned)rl8;           // row within 32KB subtile
    unsigned n = 2u * R + (cB >> 2);
    b1s[j] = n * 1536u + (rr >> 5) * 64u + (cB & 3u) * 16u; // + step*128
    b1d[j] = rr * 1024u + ldst;
  }
  unsigned b2s[2], b2d[2];
#pragma unroll
  for (int j = 0; j < 2; j++) {
    unsigned rr = (unsigned)(wid + 16 * j);                 // 0..31
    unsigned R = 8u * (rr & 15u) + (unsigned)rl8;
    unsigned n = 2u * R + (cB >> 2);
    b2s[j] = n * 1024u + (rr >> 4) * 64u + (cB & 3u) * 16u;
    b2d[j] = rr * 1024u + ldst;
  }
  unsigned b3s, b3d;
  {
    unsigned rr = (unsigned)wid;                            // 0..15
    unsigned R = 8u * (rr & 7u) + (unsigned)rl8;
    unsigned n = 2u * R + (cB >> 2);
    b3s = n * 512u + (rr >> 3) * 64u + (cB & 3u) * 16u;
    b3d = rr * 1024u + ldst;
  }

  // ================= phase 1: (64x768 fp32 -> bf16) @ zT1 -> 64x512, 12 steps =================
  float ss = 0.f;
  {
    float4 p0 = *(const float4*)a1g;
    ss += stage_a4(p0, A1 + a1d);                           // tile 0 -> buf0
  }
  float4 pA = *(const float4*)(a1g + 256);                  // tile 1 in flight
#pragma unroll
  for (int j = 0; j < 4; j++) gld16((const char*)zt1 + b1s[j], B1 + b1d[j]);

  ffrag4 acc1[2][4];
#pragma unroll
  for (int a = 0; a < 2; a++)
#pragma unroll
    for (int b = 0; b < 4; b++) acc1[a][b] = (ffrag4){0.f, 0.f, 0.f, 0.f};

  for (int k = 0; k < 12; k++) {
    __syncthreads();  // drains staging for tile k (vm + lgkm); prior readers of nxt done
    char* curA = A1 + (k & 1) * 8192;
    char* curB = B1 + (k & 1) * 65536;
    if (k < 11) {
      char* nA = A1 + ((k + 1) & 1) * 8192;
      char* nB = B1 + ((k + 1) & 1) * 65536;
      unsigned adv = (unsigned)(k + 1) * 128u;
#pragma unroll
      for (int j = 0; j < 4; j++) gld16((const char*)zt1 + b1s[j] + adv, nB + b1d[j]);
      ss += stage_a4(pA, nA + a1d);                         // tile k+1 (landed via barrier)
      if (k < 10) pA = *(const float4*)(a1g + (size_t)(k + 2) * 256);
    }
#pragma unroll
    for (int kt = 0; kt < 2; kt++) {
      bfrag8 a0 = *(const bfrag8*)(curA + kt * 4096 + afoff[0]);
      bfrag8 a1f = *(const bfrag8*)(curA + kt * 4096 + afoff[1]);
#pragma unroll
      for (int tn = 0; tn < 4; tn++) {
        bfrag8 bf = *(const bfrag8*)(curB + kt * 32768 + bf1off[tn]);
        acc1[0][tn] = __builtin_amdgcn_mfma_f32_16x16x32_bf16(a0, bf, acc1[0][tn], 0, 0, 0);
        acc1[1][tn] = __builtin_amdgcn_mfma_f32_16x16x32_bf16(a1f, bf, acc1[1][tn], 0, 0, 0);
      }
    }
  }

  // ---- epilogue 1 ----
  __syncthreads();  // all phase-1 LDS reads done; A1/B1 dead
#pragma unroll
  for (int j = 0; j < 2; j++) gld16((const char*)zt2 + b2s[j], B2 + b2d[j]);  // B2 tile 0

  // lambda0: reduce ss over the 16 lanes sharing a row (each x element counted exactly once)
  ss += __shfl_xor(ss, 1); ss += __shfl_xor(ss, 2);
  ss += __shfl_xor(ss, 4); ss += __shfl_xor(ss, 8);
  if ((lane & 15) == 0) lamS[mrow] = 2.f / (1.f - CURV * ss);
  if (t < 64) { sums[0][t] = 0.f; sums[1][t] = 0.f; }
  __syncthreads();  // lamS/sums visible

  const float cs = sqrtf(CURV), inv_cs = 1.f / cs;
  poly_w<4>(acc1, st1, wn, lm, wm, quad, lamS, cs, inv_cs);
  reduce_rows<4, false>(acc1, nullptr, lm, wm, quad, sums);
  __syncthreads();
  if (t < 64) {
    float sw2 = sums[0][t], swp2 = sums[1][t];
    float den = 1.f + sqrtf(1.f + CURV * sw2);
    float nn = fmaxf(sqrtf(sw2) / den, EPSF);
    float al = atanhf(fminf(cs * nn, 1.f - 1e-7f)) / (cs * nn);
    float vn = fmaxf(al * sqrtf(swp2) / den, EPSF);
    float be = tanhf(cs * vn) / (cs * vn);
    float gam = al * be / den;
    gamS[t] = gam;
    lamS[t] = 2.f / (1.f - CURV * gam * gam * swp2);
  }
  __syncthreads();
  panel_write<4>(acc1, H1, lm, wm, wn, quad, gamS);  // H1 overlays dead A1/B1 head
  if (t < 64) { sums[0][t] = 0.f; sums[1][t] = 0.f; }

  // ================= phase 2: h1(64x512) @ zT2 -> 64x256, 8 steps =================
  ffrag4 acc2[2][2];
#pragma unroll
  for (int a = 0; a < 2; a++)
#pragma unroll
    for (int b = 0; b < 2; b++) acc2[a][b] = (ffrag4){0.f, 0.f, 0.f, 0.f};

  for (int k = 0; k < 8; k++) {
    __syncthreads();  // k=0: drains B2 tile0 + panel_write; tile k ready
    char* curB = B2 + (k & 1) * 32768;
    if (k < 7) {
      char* nB = B2 + ((k + 1) & 1) * 32768;
      unsigned adv = (unsigned)(k + 1) * 128u;
#pragma unroll
      for (int j = 0; j < 2; j++) gld16((const char*)zt2 + b2s[j] + adv, nB + b2d[j]);
    }
#pragma unroll
    for (int kt = 0; kt < 2; kt++) {
      bfrag8 a0 = *(const bfrag8*)(H1 + (2 * k + kt) * 4096 + afoff[0]);
      bfrag8 a1f = *(const bfrag8*)(H1 + (2 * k + kt) * 4096 + afoff[1]);
#pragma unroll
      for (int tn = 0; tn < 2; tn++) {
        bfrag8 bf = *(const bfrag8*)(curB + kt * 16384 + bf2off[tn]);
        acc2[0][tn] = __builtin_amdgcn_mfma_f32_16x16x32_bf16(a0, bf, acc2[0][tn], 0, 0, 0);
        acc2[1][tn] = __builtin_amdgcn_mfma_f32_16x16x32_bf16(a1f, bf, acc2[1][tn], 0, 0, 0);
      }
    }
  }

  // ---- epilogue 2 ----
  __syncthreads();  // phase-2 reads done; H1/B2 dead
  gld16((const char*)zt3 + b3s, B3 + b3d);  // B3 tile 0 -> [32K,48K)
  poly_w<2>(acc2, st2, wn, lm, wm, quad, lamS, cs, inv_cs);
  reduce_rows<2, false>(acc2, nullptr, lm, wm, quad, sums);
  __syncthreads();
  if (t < 64) {
    float sw2 = sums[0][t], swp2 = sums[1][t];
    float den = 1.f + sqrtf(1.f + CURV * sw2);
    float nn = fmaxf(sqrtf(sw2) / den, EPSF);
    float al = atanhf(fminf(cs * nn, 1.f - 1e-7f)) / (cs * nn);
    float vn = fmaxf(al * sqrtf(swp2) / den, EPSF);
    float be = tanhf(cs * vn) / (cs * vn);
    float gam = al * be / den;
    gamS[t] = gam;
    lamS[t] = 2.f / (1.f - CURV * gam * gam * swp2);
  }
  __syncthreads();
  panel_write<2>(acc2, H2, lm, wm, wn, quad, gamS);  // H2 overlays dead H1 head
  if (t < 64) { sums[0][t] = 0.f; sums[1][t] = 0.f; sums[2][t] = 0.f; }

  // ================= phase 3: h2(64x256) @ zT3 -> 64x128 (+ layer-4 dot), 4 steps ==========
  ffrag4 acc3[2][1];
  acc3[0][0] = (ffrag4){0.f, 0.f, 0.f, 0.f};
  acc3[1][0] = (ffrag4){0.f, 0.f, 0.f, 0.f};
  float z4v[1] = { z4[wn * 16 + lm] };

  for (int k = 0; k < 4; k++) {
    __syncthreads();  // k=0: drains B3 tile0 + panel_write
    char* curB = B3 + (k & 1) * 16384;
    if (k < 3)
      gld16((const char*)zt3 + b3s + (unsigned)(k + 1) * 128u,
            B3 + ((k + 1) & 1) * 16384 + b3d);
#pragma unroll
    for (int kt = 0; kt < 2; kt++) {
      bfrag8 a0 = *(const bfrag8*)(H2 + (2 * k + kt) * 4096 + afoff[0]);
      bfrag8 a1f = *(const bfrag8*)(H2 + (2 * k + kt) * 4096 + afoff[1]);
      bfrag8 bf = *(const bfrag8*)(curB + kt * 8192 + bf3off);
      acc3[0][0] = __builtin_amdgcn_mfma_f32_16x16x32_bf16(a0, bf, acc3[0][0], 0, 0, 0);
      acc3[1][0] = __builtin_amdgcn_mfma_f32_16x16x32_bf16(a1f, bf, acc3[1][0], 0, 0, 0);
    }
  }
  __syncthreads();

  poly_w<1>(acc3, st3, wn, lm, wm, quad, lamS, cs, inv_cs);
  reduce_rows<1, true>(acc3, z4v, lm, wm, quad, sums);
  __syncthreads();
  if (t < 64) {
    float sw2 = sums[0][t], swp2 = sums[1][t];
    float den = 1.f + sqrtf(1.f + CURV * sw2);
    float nn = fmaxf(sqrtf(sw2) / den, EPSF);
    float al = atanhf(fminf(cs * nn, 1.f - 1e-7f)) / (cs * nn);
    float vn = fmaxf(al * sqrtf(swp2) / den, EPSF);
    float be = tanhf(cs * vn) / (cs * vn);
    float gam = al * be / den;
    float s = gam * sums[2][t];
    float lamh = 2.f / (1.f - CURV * gam * gam * swp2);
    float g = cs * lamh * s * st4[1] - (lamh - 1.f) * st4[2];
    float q = g * g;
    float u = g * (1.f - q * (1.f / 6.f) + q * q * 0.075f - q * q * q * 0.044642857f);
    float d1 = st4[0] * u;
    float S = 2.f * g * sqrtf(1.f + q);
    float Ch = 1.f + 2.f * q;
    float w = (S * (1.f + 0.5f * d1 * d1) + Ch * d1) * inv_cs;
    outF[rowg0 + t] = w / (1.f + sqrtf(1.f + CURV * w * w));
  }
}

extern "C" void kernel_launch(void* const* d_in, const int* in_sizes, int n_in,
                              void* d_out, int out_size, void* d_ws, size_t ws_size,
                              hipStream_t stream) {
  const float* x  = (const float*)d_in[0];
  const float* z1 = (const float*)d_in[1];
  const float* b1 = (const float*)d_in[2];
  const float* z2 = (const float*)d_in[3];
  const float* b2 = (const float*)d_in[4];
  const float* z3 = (const float*)d_in[5];
  const float* b3 = (const float*)d_in[6];
  const float* z4 = (const float*)d_in[7];
  const float* b4 = (const float*)d_in[8];

  char* ws = (char*)d_ws; size_t off = 0;
  auto carve = [&](size_t b) { char* p = ws + off; off += (b + 255) & ~(size_t)255; return p; };
  unsigned short* zT1 = (unsigned short*)carve(512 * 768 * 2);
  unsigned short* zT2 = (unsigned short*)carve(256 * 512 * 2);
  unsigned short* zT3 = (unsigned short*)carve(128 * 256 * 2);
  unsigned short* zT4 = (unsigned short*)carve(128 * 2);
  float* st1 = (float*)carve(512 * 4 * 4);
  float* st2 = (float*)carve(256 * 4 * 4);
  float* st3 = (float*)carve(128 * 4 * 4);
  float* st4 = (float*)carve(4 * 4);

  prep_all<<<897, 128, 0, stream>>>(z1, b1, z2, b2, z3, b3, z4, b4,
                                    zT1, st1, zT2, st2, zT3, st3, zT4, st4);
  fused_mlp<<<1024, 1024, 0, stream>>>(x, zT1, st1, zT2, st2, zT3, st3, z4, st4, (float*)d_out);
}